// Round 6
// baseline (164.997 us; speedup 1.0000x reference)
//
#include <hip/hip_runtime.h>
#include <math.h>

#define EPS 1e-12f

typedef float f4 __attribute__((ext_vector_type(4)));

// ---------------------------------------------------------------------------
// FUSED single-launch version.
// Stage A (768 blocks x 512 thr): per-pixel sum-of-squares partials with
// 1 KB-contiguous wave loads (same geometry as R4, plain f4 loads).
// Then a device-scope last-arriver gate: per (tensor,b) group counter; the
// last 3 arrivals of each group become the k=3/5/7 consumers and run the
// tile-MSE in-block (partials are L2-resident). A second counter elects the
// 48th tile-finisher to sum the 48 MSEs deterministically into out[0].
// Kills the second launch + inter-dispatch drain barrier; overlaps stage 2
// under the remaining producers' tails.
// Deadlock-safety: 31.6 KB LDS -> 4 blocks/CU; 768 blocks < 1024 co-resident
// capacity, and the gate doesn't even require co-residency (each block
// increments exactly once; counters monotonically reach N).
// ---------------------------------------------------------------------------
template <int PLANE, int C, int CS_N>
__device__ __forceinline__ void partial_tile(
    const float* __restrict__ xo, const float* __restrict__ xg,
    float* __restrict__ part,   // [2][8][CS_N][PLANE]
    int b, int tile, int cs, int tid, float* lds /* 4096 floats */)
{
    constexpr int SLABF = 256;              // floats per channel-slab (1 KB)
    constexpr int CG    = 8;                // channel groups (one per wave)
    constexpr int CPT   = (C / CS_N) / CG;  // channels per thread = 8
    static_assert(CPT == 8, "geometry");

    const int quad = tid & 63;              // wave lanes cover 1 KB slab
    const int cg   = tid >> 6;              // wave id = channel group
    const int base = b * C * PLANE + tile * SLABF + quad * 4;
    const int c0   = cs * (C / CS_N) + cg * CPT;

    f4 so = {0.f, 0.f, 0.f, 0.f};
    f4 sg = {0.f, 0.f, 0.f, 0.f};
#pragma unroll
    for (int ib = 0; ib < CPT / 4; ++ib) {
        f4 vo[4], vg[4];
#pragma unroll
        for (int u = 0; u < 4; ++u) {
            const int off = base + (c0 + ib * 4 + u) * PLANE;
            vo[u] = *reinterpret_cast<const f4*>(xo + off);
            vg[u] = *reinterpret_cast<const f4*>(xg + off);
        }
#pragma unroll
        for (int u = 0; u < 4; ++u) {
            so += vo[u] * vo[u];
            sg += vg[u] * vg[u];
        }
    }

    // lds layout: [2 streams][CG][SLABF]
    *reinterpret_cast<f4*>(lds + (0 * CG + cg) * SLABF + quad * 4) = so;
    *reinterpret_cast<f4*>(lds + (1 * CG + cg) * SLABF + quad * 4) = sg;
    __syncthreads();

    // combine across the 8 channel groups; write 256 px x 2 streams partials
    if (tid < 128) {
        const int s = tid >> 6;
        const int q = tid & 63;
        f4 a = {0.f, 0.f, 0.f, 0.f};
#pragma unroll
        for (int g = 0; g < CG; ++g)
            a += *reinterpret_cast<const f4*>(lds + (s * CG + g) * SLABF + q * 4);
        *reinterpret_cast<f4*>(
            part + ((s * 8 + b) * CS_N + cs) * PLANE + tile * SLABF + q * 4) = a;
    }
}

// ---------------------------------------------------------------------------
// tile-MSE for one (tensor, b, K): combine CS channel-split partials -> p ->
// diff -> row K-window -> col K-window -> squared mean. Returns mean on tid 0.
// ---------------------------------------------------------------------------
template <int H, int K, int CS>
__device__ __forceinline__ float tile_mse(
    const float* __restrict__ po, const float* __restrict__ pg, int tid,
    float* d /* H*H (reuses stage-A lds) */, float* rbuf, float* wsum)
{
    constexpr int V = H - K + 1;
    constexpr int PLANE = H * H;

    // per-pixel totals across CS splits, then d = p_out - p_gt
    for (int q = tid; q < PLANE / 4; q += 512) {
        f4 ao = {0.f, 0.f, 0.f, 0.f};
        f4 ag = {0.f, 0.f, 0.f, 0.f};
#pragma unroll
        for (int c = 0; c < CS; ++c) {
            ao += *reinterpret_cast<const f4*>(po + c * PLANE + q * 4);
            ag += *reinterpret_cast<const f4*>(pg + c * PLANE + q * 4);
        }
        f4 dd;
#pragma unroll
        for (int j = 0; j < 4; ++j) {
            const float no = sqrtf(ao[j]);
            const float ng = sqrtf(ag[j]);
            dd[j] = ao[j] / fmaxf(no, EPS) - ag[j] / fmaxf(ng, EPS);
        }
        *reinterpret_cast<f4*>(d + q * 4) = dd;
    }
    __syncthreads();

    // row K-window sums -> rbuf[H][V] (packed stride V)
    for (int i = tid; i < H * V; i += 512) {
        const int y = i / V;            // compile-time V -> magic-mul
        const int x = i - y * V;
        float s = 0.f;
#pragma unroll
        for (int j = 0; j < K; ++j) s += d[y * H + x + j];
        rbuf[i] = s;
    }
    __syncthreads();

    // column K-window sums + squared accumulate
    float acc = 0.f;
    for (int i = tid; i < V * V; i += 512) {
        const int y = i / V;
        const int x = i - y * V;
        float s = 0.f;
#pragma unroll
        for (int j = 0; j < K; ++j) s += rbuf[(y + j) * V + x];
        acc = fmaf(s, s, acc);
    }

    // block reduction (wave64 shuffle, then LDS across 8 waves)
    for (int off = 32; off > 0; off >>= 1) acc += __shfl_down(acc, off);
    if ((tid & 63) == 0) wsum[tid >> 6] = acc;
    __syncthreads();
    float total = 0.f;
    if (tid == 0) {
#pragma unroll
        for (int wv = 0; wv < 8; ++wv) total += wsum[wv];
        total /= (float)(8 * V * V);    // mean over [B, V, V]
    }
    return total;
}

__global__ __launch_bounds__(512) void fused_kernel(
    const float* __restrict__ o0, const float* __restrict__ g0,
    const float* __restrict__ o1, const float* __restrict__ g1,
    float* __restrict__ part0, float* __restrict__ part1,
    unsigned* __restrict__ ctrl,   // [16] group counters + [16] tile counter
    float* __restrict__ msebuf,    // [48]
    float* __restrict__ out)
{
    __shared__ float lds[4096];          // stage A staging / stage B d-plane
    __shared__ float rbuf[64 * 62];      // row-window sums
    __shared__ float wsum[8];
    __shared__ unsigned s_tk;

    const int bid = blockIdx.x;
    const int tid = threadIdx.x;

    int t, b, g, N;
    if (bid < 512) {
        // t0: b(8) x tile(16: 4 rows) x cs(4: 64ch)
        t = 0; b = bid >> 6;
        const int tile = (bid >> 2) & 15, cs = bid & 3;
        partial_tile<4096, 256, 4>(o0, g0, part0, b, tile, cs, tid, lds);
        g = b; N = 64;
    } else {
        // t1: b(8) x tile(4: 8 rows) x cs(8: 64ch)
        t = 1;
        const int e = bid - 512; b = e >> 5;
        const int tile = (e >> 3) & 3, cs = e & 7;
        partial_tile<1024, 512, 8>(o1, g1, part1, b, tile, cs, tid, lds);
        g = 8 + b; N = 32;
    }

    // ensure ALL threads' partial stores are issued before the release-add
    __syncthreads();

    // group arrival; release makes this block's partials device-visible
    if (tid == 0)
        s_tk = __hip_atomic_fetch_add(&ctrl[g], 1u,
                                      __ATOMIC_ACQ_REL, __HIP_MEMORY_SCOPE_AGENT);
    __syncthreads();
    const int tk = (int)s_tk;
    if (tk < N - 3) return;              // pure producer: done
    const int ki = N - 1 - tk;           // 0,1,2 -> K = 3,5,7

    // wait until the whole group's partials are visible
    if (tid == 0) {
        while (__hip_atomic_load(&ctrl[g], __ATOMIC_ACQUIRE,
                                 __HIP_MEMORY_SCOPE_AGENT) != (unsigned)N) {
            __builtin_amdgcn_s_sleep(1);
        }
    }
    __syncthreads();

    float s = 0.f;
    if (t == 0) {
        const float* po = part0 + (0 * 8 + b) * 4 * 4096;
        const float* pg = part0 + (1 * 8 + b) * 4 * 4096;
        if      (ki == 0) s = tile_mse<64, 3, 4>(po, pg, tid, lds, rbuf, wsum);
        else if (ki == 1) s = tile_mse<64, 5, 4>(po, pg, tid, lds, rbuf, wsum);
        else              s = tile_mse<64, 7, 4>(po, pg, tid, lds, rbuf, wsum);
    } else {
        const float* po = part1 + (0 * 8 + b) * 8 * 1024;
        const float* pg = part1 + (1 * 8 + b) * 8 * 1024;
        if      (ki == 0) s = tile_mse<32, 3, 8>(po, pg, tid, lds, rbuf, wsum);
        else if (ki == 1) s = tile_mse<32, 5, 8>(po, pg, tid, lds, rbuf, wsum);
        else              s = tile_mse<32, 7, 8>(po, pg, tid, lds, rbuf, wsum);
    }

    if (tid == 0) {
        msebuf[g * 3 + ki] = s;          // covered by the release below
        const unsigned t2 = __hip_atomic_fetch_add(
            &ctrl[16], 1u, __ATOMIC_ACQ_REL, __HIP_MEMORY_SCOPE_AGENT);
        if (t2 == 47u) {                 // 48th finisher: deterministic sum
            float tot = 0.f;
            for (int i = 0; i < 48; ++i)
                tot += __hip_atomic_load(&msebuf[i], __ATOMIC_RELAXED,
                                         __HIP_MEMORY_SCOPE_AGENT);
            out[0] = tot;
        }
    }
}

extern "C" void kernel_launch(void* const* d_in, const int* in_sizes, int n_in,
                              void* d_out, int out_size, void* d_ws, size_t ws_size,
                              hipStream_t stream) {
    // setup_inputs order: out_feat0, out_feat1, gt_feat0, gt_feat1
    const float* out_feat0 = (const float*)d_in[0];  // [8, 256, 64, 64]
    const float* out_feat1 = (const float*)d_in[1];  // [8, 512, 32, 32]
    const float* gt_feat0  = (const float*)d_in[2];
    const float* gt_feat1  = (const float*)d_in[3];
    float* out = (float*)d_out;

    float*    part0  = (float*)d_ws;                    // [2][8][4][4096] = 1 MB
    float*    part1  = part0 + 2 * 8 * 4 * 4096;        // [2][8][8][1024] = 0.5 MB
    unsigned* ctrl   = (unsigned*)((char*)d_ws + (2u << 20));       // 17 counters
    float*    msebuf = (float*)((char*)d_ws + (2u << 20) + 256);    // 48 floats

    hipMemsetAsync(ctrl, 0, 128, stream);  // zero counters (graph-capturable)
    fused_kernel<<<768, 512, 0, stream>>>(
        out_feat0, gt_feat0, out_feat1, gt_feat1,
        part0, part1, ctrl, msebuf, out);
}

// Round 7
// 130.477 us; speedup vs baseline: 1.2646x; 1.2646x over previous
//
#include <hip/hip_runtime.h>
#include <math.h>

#define EPS 1e-12f

typedef float f4 __attribute__((ext_vector_type(4)));

// ---------------------------------------------------------------------------
// Stage 1 "page-run": 256 thr (4 waves). Block = (b, 4KB-pixel-tile, 16-ch
// split). Each wave owns 4 CONTIGUOUS channels and reads each channel's 4KB
// tile as 4 sequential 1KB wave-loads (t0: 4KB runs @16KB stride, 4x longer
// DRAM-page runs than R4; t1: the 4 channels are contiguous -> fully
// sequential 16KB per wave-stream). Register accumulators per 1KB subslab
// (8 x f4 = 32 VGPR), LDS combine across the 4 waves, partials to ws.
// Theory: R4's 1KB@16KB-stride reads are page-activate-bound (~3.3 TB/s);
// 4x longer runs should approach the fill's ~6.5 TB/s regime.
// ---------------------------------------------------------------------------
template <int PLANE, int C, int CS_N>
__device__ __forceinline__ void partial_tile(
    const float* __restrict__ xo, const float* __restrict__ xg,
    float* __restrict__ part,   // [2][8][CS_N][PLANE]
    int b, int tile, int cs, int tid, float* lds /* 2048 floats */)
{
    const int lane = tid & 63;
    const int cg   = tid >> 6;            // 0..3 (wave id)
    const int c0   = cs * 16 + cg * 4;    // wave's first channel (contiguous 4)
    const int base = b * C * PLANE + tile * 1024 + lane * 4;

    f4 ao[4] = {{0,0,0,0},{0,0,0,0},{0,0,0,0},{0,0,0,0}};
    f4 ag[4] = {{0,0,0,0},{0,0,0,0},{0,0,0,0},{0,0,0,0}};
#pragma unroll 1
    for (int ch = 0; ch < 4; ++ch) {
        const int coff = base + (c0 + ch) * PLANE;
        f4 vo[4], vg[4];
#pragma unroll
        for (int j = 0; j < 4; ++j)
            vo[j] = *reinterpret_cast<const f4*>(xo + coff + j * 256);
#pragma unroll
        for (int j = 0; j < 4; ++j)
            vg[j] = *reinterpret_cast<const f4*>(xg + coff + j * 256);
#pragma unroll
        for (int j = 0; j < 4; ++j) {
            ao[j] += vo[j] * vo[j];
            ag[j] += vg[j] * vg[j];
        }
    }

    // cross-wave combine, one 1KB subslab at a time (LDS 8 KB)
#pragma unroll
    for (int j = 0; j < 4; ++j) {
        *reinterpret_cast<f4*>(lds + (0 * 4 + cg) * 256 + lane * 4) = ao[j];
        *reinterpret_cast<f4*>(lds + (1 * 4 + cg) * 256 + lane * 4) = ag[j];
        __syncthreads();
        if (tid < 128) {
            const int s = tid >> 6;       // stream
            const int q = tid & 63;       // pixel-quad
            f4 a = {0.f, 0.f, 0.f, 0.f};
#pragma unroll
            for (int g = 0; g < 4; ++g)
                a += *reinterpret_cast<const f4*>(lds + (s * 4 + g) * 256 + q * 4);
            *reinterpret_cast<f4*>(
                part + ((s * 8 + b) * CS_N + cs) * PLANE + tile * 1024 + j * 256 + q * 4) = a;
        }
        __syncthreads();
    }
}

__global__ __launch_bounds__(256) void stage1_kernel(
    const float* __restrict__ o0, const float* __restrict__ g0,
    const float* __restrict__ o1, const float* __restrict__ g1,
    float* __restrict__ part0, float* __restrict__ part1,
    float* __restrict__ out)
{
    __shared__ float lds[2048];
    const int bid = blockIdx.x;
    if (bid == 0 && threadIdx.x == 0) out[0] = 0.0f;  // stage 2 atomicAdds
    if (bid < 512) {
        // t0: b(8) x tile(4: quarter-plane 4KB) x cs(16: 16ch)
        const int b = bid >> 6, tile = (bid >> 4) & 3, cs = bid & 15;
        partial_tile<4096, 256, 16>(o0, g0, part0, b, tile, cs, threadIdx.x, lds);
    } else {
        // t1: b(8) x tile(1: full 4KB plane) x cs(32: 16ch)
        const int e = bid - 512;
        const int b = e >> 5, cs = e & 31;
        partial_tile<1024, 512, 32>(o1, g1, part1, b, 0, cs, threadIdx.x, lds);
    }
}

// ---------------------------------------------------------------------------
// Stage 2 (templated): per (tensor t, batch b, kernel k) block: combine
// channel-split partials -> p -> diff -> row k-window -> col k-window ->
// squared mean -> atomicAdd. Partials are ~6 MB (L2/L3-resident).
// ---------------------------------------------------------------------------
template <int H, int K, int CS>
__device__ __forceinline__ void tile_mse(
    const float* __restrict__ po, const float* __restrict__ pg,
    float* __restrict__ out, int tid,
    float* d /* H*H */, float* rbuf /* H*(H-K+1) */, float* wsum /* 8 */)
{
    constexpr int V = H - K + 1;
    constexpr int PLANE = H * H;

    // per-pixel totals across CS splits, then d = p_out - p_gt
    for (int q = tid; q < PLANE / 4; q += 512) {
        f4 ao = {0.f, 0.f, 0.f, 0.f};
        f4 ag = {0.f, 0.f, 0.f, 0.f};
#pragma unroll 4
        for (int c = 0; c < CS; ++c) {
            ao += *reinterpret_cast<const f4*>(po + c * PLANE + q * 4);
            ag += *reinterpret_cast<const f4*>(pg + c * PLANE + q * 4);
        }
        f4 dd;
#pragma unroll
        for (int j = 0; j < 4; ++j) {
            const float no = sqrtf(ao[j]);
            const float ng = sqrtf(ag[j]);
            dd[j] = ao[j] / fmaxf(no, EPS) - ag[j] / fmaxf(ng, EPS);
        }
        *reinterpret_cast<f4*>(d + q * 4) = dd;
    }
    __syncthreads();

    // row K-window sums -> rbuf[H][V] (packed stride V)
    for (int i = tid; i < H * V; i += 512) {
        const int y = i / V;            // compile-time V -> magic-mul
        const int x = i - y * V;
        float s = 0.f;
#pragma unroll
        for (int j = 0; j < K; ++j) s += d[y * H + x + j];
        rbuf[i] = s;
    }
    __syncthreads();

    // column K-window sums + squared accumulate
    float acc = 0.f;
    for (int i = tid; i < V * V; i += 512) {
        const int y = i / V;
        const int x = i - y * V;
        float s = 0.f;
#pragma unroll
        for (int j = 0; j < K; ++j) s += rbuf[(y + j) * V + x];
        acc = fmaf(s, s, acc);
    }

    // block reduction (wave64 shuffle, then LDS across 8 waves)
    for (int off = 32; off > 0; off >>= 1) acc += __shfl_down(acc, off);
    if ((tid & 63) == 0) wsum[tid >> 6] = acc;
    __syncthreads();
    if (tid == 0) {
        float total = 0.f;
#pragma unroll
        for (int wv = 0; wv < 8; ++wv) total += wsum[wv];
        atomicAdd(out, total / (float)(8 * V * V));  // mean over [B, V, V]
    }
}

__global__ __launch_bounds__(512) void stage2_kernel(
    const float* __restrict__ part0, const float* __restrict__ part1,
    float* __restrict__ out)
{
    __shared__ float d[4096];            // diff plane (t0: 16 KB)
    __shared__ float rbuf[64 * 62];      // row-window sums [H][V]
    __shared__ float wsum[8];

    const int bid = blockIdx.x;          // [0, 48)
    const int t   = bid / 24;
    const int rem = bid % 24;
    const int b   = rem / 3;
    const int ki  = rem % 3;
    const int tid = threadIdx.x;

    if (t == 0) {
        const float* po = part0 + (0 * 8 + b) * 16 * 4096;
        const float* pg = part0 + (1 * 8 + b) * 16 * 4096;
        if      (ki == 0) tile_mse<64, 3, 16>(po, pg, out, tid, d, rbuf, wsum);
        else if (ki == 1) tile_mse<64, 5, 16>(po, pg, out, tid, d, rbuf, wsum);
        else              tile_mse<64, 7, 16>(po, pg, out, tid, d, rbuf, wsum);
    } else {
        const float* po = part1 + (0 * 8 + b) * 32 * 1024;
        const float* pg = part1 + (1 * 8 + b) * 32 * 1024;
        if      (ki == 0) tile_mse<32, 3, 32>(po, pg, out, tid, d, rbuf, wsum);
        else if (ki == 1) tile_mse<32, 5, 32>(po, pg, out, tid, d, rbuf, wsum);
        else              tile_mse<32, 7, 32>(po, pg, out, tid, d, rbuf, wsum);
    }
}

extern "C" void kernel_launch(void* const* d_in, const int* in_sizes, int n_in,
                              void* d_out, int out_size, void* d_ws, size_t ws_size,
                              hipStream_t stream) {
    // setup_inputs order: out_feat0, out_feat1, gt_feat0, gt_feat1
    const float* out_feat0 = (const float*)d_in[0];  // [8, 256, 64, 64]
    const float* out_feat1 = (const float*)d_in[1];  // [8, 512, 32, 32]
    const float* gt_feat0  = (const float*)d_in[2];
    const float* gt_feat1  = (const float*)d_in[3];
    float* out = (float*)d_out;

    float* part0 = (float*)d_ws;                    // [2][8][16][4096] = 4 MB
    float* part1 = part0 + 2 * 8 * 16 * 4096;       // [2][8][32][1024] = 2 MB

    stage1_kernel<<<768, 256, 0, stream>>>(
        out_feat0, gt_feat0, out_feat1, gt_feat1, part0, part1, out);
    stage2_kernel<<<48, 512, 0, stream>>>(part0, part1, out);
}